// Round 3
// baseline (1328.363 us; speedup 1.0000x reference)
//
#include <hip/hip_runtime.h>

// GraphSAGE 2-layer, N=100000 nodes, d=64, E=1.6M edges, fp32.
// per layer: out = relu( (scatter_sum(x)@Wl^T) * inv_cnt + b + x@Wr^T )
//   = dense GEMM (Z = X@Wl^T, P = X@Wr^T + b) + bucketed edge aggregation.
// R3: replaced per-node CSR (fill_k had 17x write amplification, 108MB HBM
// writes for 6.4MB payload) with coarse dst-buckets (500 x 200 nodes):
//   bcount/bscan -> bscatter (LDS-batched, coalesced ~64B runs) -> bagg
//   (per-bucket LDS float accumulators, ds_add_f32, local counts).

#define NFEAT 64
#define GR 8        // rows per wave in GEMM
#define NPB 200     // nodes per bucket
#define NBUCK 500   // ceil(100000/200)
#define TILE 4096   // edges per bscatter block (512 thr x 8)

// ---------------- bucket count ----------------
__global__ __launch_bounds__(256) void bcount_k(const int* __restrict__ dst,
                                                int* __restrict__ gcnt, int E) {
  __shared__ int c[NBUCK];
  int tid = threadIdx.x;
  for (int t = tid; t < NBUCK; t += 256) c[t] = 0;
  __syncthreads();
  int stride = gridDim.x * 256 * 4;
  for (int i = (blockIdx.x * 256 + tid) * 4; i < E; i += stride) {
    if (i + 3 < E) {
      int4 d = *(const int4*)(dst + i);
      atomicAdd(&c[d.x / NPB], 1); atomicAdd(&c[d.y / NPB], 1);
      atomicAdd(&c[d.z / NPB], 1); atomicAdd(&c[d.w / NPB], 1);
    } else {
      for (int e = i; e < E; ++e) atomicAdd(&c[dst[e] / NPB], 1);
    }
  }
  __syncthreads();
  for (int t = tid; t < NBUCK; t += 256)
    if (c[t]) atomicAdd(&gcnt[t], c[t]);
}

// ---------------- bucket scan (1 block) ----------------
__global__ __launch_bounds__(512) void bscan_k(const int* __restrict__ gcnt,
                                               int* __restrict__ goff,
                                               int* __restrict__ gcur) {
  __shared__ int s[512];
  int t = threadIdx.x;
  int v = (t < NBUCK) ? gcnt[t] : 0;
  s[t] = v;
  __syncthreads();
  for (int d = 1; d < 512; d <<= 1) {
    int add = (t >= d) ? s[t - d] : 0;
    __syncthreads();
    s[t] += add;
    __syncthreads();
  }
  if (t < NBUCK) {
    int o = s[t] - v;          // exclusive
    goff[t] = o;
    gcur[t] = o;
    if (t == NBUCK - 1) goff[NBUCK] = s[t];
  }
}

// ---------------- bucketed scatter: edges -> bucket-grouped int2 pairs ----
__global__ __launch_bounds__(512) void bscatter_k(const int* __restrict__ src,
                                                  const int* __restrict__ dst,
                                                  int* __restrict__ gcur,
                                                  int2* __restrict__ pairs, int E) {
  __shared__ int lcnt[NBUCK];
  __shared__ int loff[NBUCK];
  __shared__ int lcur[NBUCK];
  __shared__ int lbase[NBUCK];
  __shared__ int s[512];
  __shared__ int s_src[TILE];
  __shared__ int s_dst[TILE];
  __shared__ int s_tgt[TILE];

  int tid = threadIdx.x;
  int tileStart = blockIdx.x * TILE;
  int tileCnt = E - tileStart; if (tileCnt > TILE) tileCnt = TILE;

  for (int t = tid; t < NBUCK; t += 512) lcnt[t] = 0;
  __syncthreads();

  // load up to 8 edges into registers
  int es[8], ed[8], eb[8];
  int base = tileStart + tid * 8;
  int ne = 0;
  if (base + 7 < E) {
    int4 a0 = *(const int4*)(src + base);
    int4 a1 = *(const int4*)(src + base + 4);
    int4 b0 = *(const int4*)(dst + base);
    int4 b1 = *(const int4*)(dst + base + 4);
    es[0]=a0.x; es[1]=a0.y; es[2]=a0.z; es[3]=a0.w;
    es[4]=a1.x; es[5]=a1.y; es[6]=a1.z; es[7]=a1.w;
    ed[0]=b0.x; ed[1]=b0.y; ed[2]=b0.z; ed[3]=b0.w;
    ed[4]=b1.x; ed[5]=b1.y; ed[6]=b1.z; ed[7]=b1.w;
    ne = 8;
  } else {
    for (int j = 0; j < 8 && base + j < E; ++j) {
      es[j] = src[base + j]; ed[j] = dst[base + j]; ++ne;
    }
  }
  for (int j = 0; j < ne; ++j) {
    eb[j] = ed[j] / NPB;
    atomicAdd(&lcnt[eb[j]], 1);
  }
  __syncthreads();

  // exclusive scan of lcnt (512-wide Hillis-Steele)
  int v = (tid < NBUCK) ? lcnt[tid] : 0;
  s[tid] = v;
  __syncthreads();
  for (int d = 1; d < 512; d <<= 1) {
    int add = (tid >= d) ? s[tid - d] : 0;
    __syncthreads();
    s[tid] += add;
    __syncthreads();
  }
  if (tid < NBUCK) {
    int o = s[tid] - v;
    loff[tid] = o;
    lcur[tid] = o;
    if (v) lbase[tid] = atomicAdd(&gcur[tid], v);
  }
  __syncthreads();

  // group edges by bucket into LDS staging, computing global target slots
  for (int j = 0; j < ne; ++j) {
    int b = eb[j];
    int slot = atomicAdd(&lcur[b], 1);
    s_src[slot] = es[j];
    s_dst[slot] = ed[j];
    s_tgt[slot] = lbase[b] + (slot - loff[b]);
  }
  __syncthreads();

  // flush: consecutive slots in a bucket -> consecutive global addrs
  for (int k = tid; k < tileCnt; k += 512) {
    pairs[s_tgt[k]] = make_int2(s_src[k], s_dst[k]);
  }
}

// ---------------- Dense GEMM: Z = X@Wl^T, P = X@Wr^T + b ----------------
__global__ __launch_bounds__(256) void gemm_k(const float* __restrict__ X,
                                              const float* __restrict__ Wl,
                                              const float* __restrict__ Wr,
                                              const float* __restrict__ b,
                                              float* __restrict__ Z,
                                              float* __restrict__ P, int n) {
  __shared__ float sWl[64 * 64];   // transposed: sWl[k*64+o] = Wl[o][k]
  __shared__ float sWr[64 * 64];
  __shared__ float sb[64];
  __shared__ float sx[4 * GR * 64];

  int tid = threadIdx.x;
  for (int idx = tid; idx < 4096; idx += 256) {
    int k = idx >> 6, o = idx & 63;
    sWl[k * 64 + o] = Wl[o * 64 + k];
    sWr[k * 64 + o] = Wr[o * 64 + k];
  }
  if (tid < 64) sb[tid] = b[tid];

  int wave = tid >> 6;
  int lane = tid & 63;
  int row0 = (blockIdx.x * 4 + wave) * GR;

  if (row0 + GR <= n) {
    const float4* xs = (const float4*)(X + (size_t)row0 * NFEAT);
    float4* sxw = (float4*)(sx + wave * (GR * 64));
    sxw[lane] = xs[lane];
    sxw[lane + 64] = xs[lane + 64];
  } else if (row0 < n) {
    for (int j = 0; j < GR; ++j) {
      if (row0 + j < n) sx[wave * (GR * 64) + j * 64 + lane] = X[(size_t)(row0 + j) * NFEAT + lane];
    }
  }
  __syncthreads();
  if (row0 >= n) return;

  float accz[GR], accp[GR];
#pragma unroll
  for (int j = 0; j < GR; ++j) { accz[j] = 0.0f; accp[j] = sb[lane]; }

  const float* xw = sx + wave * (GR * 64);
#pragma unroll 2
  for (int kk = 0; kk < 64; kk += 4) {
    float wl0 = sWl[(kk + 0) * 64 + lane];
    float wl1 = sWl[(kk + 1) * 64 + lane];
    float wl2 = sWl[(kk + 2) * 64 + lane];
    float wl3 = sWl[(kk + 3) * 64 + lane];
    float wr0 = sWr[(kk + 0) * 64 + lane];
    float wr1 = sWr[(kk + 1) * 64 + lane];
    float wr2 = sWr[(kk + 2) * 64 + lane];
    float wr3 = sWr[(kk + 3) * 64 + lane];
#pragma unroll
    for (int j = 0; j < GR; ++j) {
      float4 xk = *(const float4*)&xw[j * 64 + kk];
      accz[j] += xk.x * wl0 + xk.y * wl1 + xk.z * wl2 + xk.w * wl3;
      accp[j] += xk.x * wr0 + xk.y * wr1 + xk.z * wr2 + xk.w * wr3;
    }
  }

#pragma unroll
  for (int j = 0; j < GR; ++j) {
    int r = row0 + j;
    if (r < n) {
      Z[(size_t)r * NFEAT + lane] = accz[j];
      P[(size_t)r * NFEAT + lane] = accp[j];
    }
  }
}

// ---------------- bucket aggregation + epilogue ----------------
// One block per bucket. LDS float accumulators (pad 68 to spread banks),
// 16-lane teams: one edge per team, float4 Z-row gather, ds_add_f32.
__global__ __launch_bounds__(256) void bagg_k(const int* __restrict__ goff,
                                              const int2* __restrict__ pairs,
                                              const float* __restrict__ Z,
                                              const float* __restrict__ Pin,
                                              float* __restrict__ out, int n) {
  __shared__ float acc[NPB * 68];
  __shared__ int lcnt[NPB];

  int tid = threadIdx.x;
  int b = blockIdx.x;
  int nbase = b * NPB;
  int nn = n - nbase; if (nn > NPB) nn = NPB;
  if (nn <= 0) return;

  for (int t = tid; t < NPB * 68; t += 256) acc[t] = 0.0f;
  for (int t = tid; t < NPB; t += 256) lcnt[t] = 0;
  __syncthreads();

  int e0 = goff[b], e1 = goff[b + 1];
  int team = tid >> 4;   // 16 teams
  int q = tid & 15;

  for (int e = e0 + team; e < e1; e += 16) {
    int2 p = pairs[e];
    float4 v = *(const float4*)&Z[(size_t)p.x * NFEAT + q * 4];
    int ln = p.y - nbase;
    if (q == 0) atomicAdd(&lcnt[ln], 1);
    float* a = &acc[ln * 68 + q * 4];
    atomicAdd(a + 0, v.x);
    atomicAdd(a + 1, v.y);
    atomicAdd(a + 2, v.z);
    atomicAdd(a + 3, v.w);
  }
  __syncthreads();

  for (int idx = tid * 4; idx < nn * NFEAT; idx += 256 * 4) {
    int ln = idx >> 6;
    int f = idx & 63;
    int node = nbase + ln;
    int c = lcnt[ln];
    float iv = 1.0f / (float)(c > 1 ? c : 1);
    float4 a = *(const float4*)&acc[ln * 68 + f];
    float4 p4 = *(const float4*)&Pin[(size_t)node * NFEAT + f];
    float4 r;
    r.x = fmaxf(a.x * iv + p4.x, 0.f);
    r.y = fmaxf(a.y * iv + p4.y, 0.f);
    r.z = fmaxf(a.z * iv + p4.z, 0.f);
    r.w = fmaxf(a.w * iv + p4.w, 0.f);
    *(float4*)&out[(size_t)node * NFEAT + f] = r;
  }
}

// ---------------- launcher ----------------
extern "C" void kernel_launch(void* const* d_in, const int* in_sizes, int n_in,
                              void* d_out, int out_size, void* d_ws, size_t ws_size,
                              hipStream_t stream) {
  const float* x   = (const float*)d_in[0];
  const int*   ei  = (const int*)d_in[1];
  const float* W1l = (const float*)d_in[2];
  const float* b1  = (const float*)d_in[3];
  const float* W1r = (const float*)d_in[4];
  const float* W2l = (const float*)d_in[5];
  const float* b2  = (const float*)d_in[6];
  const float* W2r = (const float*)d_in[7];
  float* out = (float*)d_out;

  int N = in_sizes[0] / NFEAT;     // 100000
  int E = in_sizes[1] / 2;         // 1600000
  const int* srcp = ei;
  const int* dstp = ei + E;

  char* w = (char*)d_ws;
  int2*  pairs = (int2*)w;  w += (size_t)E * 8;
  float* Z     = (float*)w; w += (size_t)N * NFEAT * 4;
  float* H     = (float*)w; w += (size_t)N * NFEAT * 4;
  int*   gcnt  = (int*)w;   w += NBUCK * 4;
  int*   goff  = (int*)w;   w += (NBUCK + 1) * 4;
  int*   gcur  = (int*)w;   w += NBUCK * 4;
  if ((size_t)(w - (char*)d_ws) > ws_size) return;

  hipMemsetAsync(gcnt, 0, NBUCK * 4, stream);

  bcount_k<<<256, 256, 0, stream>>>(dstp, gcnt, E);
  bscan_k<<<1, 512, 0, stream>>>(gcnt, goff, gcur);
  int sb = (E + TILE - 1) / TILE;
  bscatter_k<<<sb, 512, 0, stream>>>(srcp, dstp, gcur, pairs, E);

  int gb = (N + 4 * GR - 1) / (4 * GR);

  // layer 1: Z = x@W1l^T ; P = x@W1r^T + b1 -> d_out ; H = relu(agg@.. + P)
  gemm_k<<<gb, 256, 0, stream>>>(x, W1l, W1r, b1, Z, out, N);
  bagg_k<<<NBUCK, 256, 0, stream>>>(goff, pairs, Z, out, H, N);
  // layer 2
  gemm_k<<<gb, 256, 0, stream>>>(H, W2l, W2r, b2, Z, out, N);
  bagg_k<<<NBUCK, 256, 0, stream>>>(goff, pairs, Z, out, out, N);
}

// Round 4
// 389.200 us; speedup vs baseline: 3.4131x; 3.4131x over previous
//
#include <hip/hip_runtime.h>

// GraphSAGE 2-layer, N=100000 nodes, d=64, E=1.6M edges, fp32.
// per layer: out = relu( (scatter_sum(x)@Wl^T) * inv_cnt + b + x@Wr^T )
//   = dense GEMM (Z = X@Wl^T, P = X@Wr^T + b) + CSR gather-mean (R2 agg_k).
// R4: CSR built via two-level scatter, every pass coalesced:
//   bcount/bscan (bucket hist) -> bscatter (bucket-grouped pairs, ~2x write
//   amp vs fill_k's 17x) -> regroup (block/bucket: LDS sort -> coalesced csr
//   + off/cnt/inv). R3's bagg_k (latency-bound, 500 blocks, 17% occ) removed.

#define NFEAT 64
#define GR 8        // rows per wave in GEMM
#define NPB 200     // nodes per bucket
#define NBUCK 500   // ceil(100000/200)
#define TILE 4096   // edges per bscatter block (512 thr x 8)
#define CAP 4608    // regroup LDS staging (bucket mean 3200, ~15 sigma margin)

// ---------------- bucket count ----------------
__global__ __launch_bounds__(256) void bcount_k(const int* __restrict__ dst,
                                                int* __restrict__ gcnt, int E) {
  __shared__ int c[NBUCK];
  int tid = threadIdx.x;
  for (int t = tid; t < NBUCK; t += 256) c[t] = 0;
  __syncthreads();
  int stride = gridDim.x * 256 * 4;
  for (int i = (blockIdx.x * 256 + tid) * 4; i < E; i += stride) {
    if (i + 3 < E) {
      int4 d = *(const int4*)(dst + i);
      atomicAdd(&c[d.x / NPB], 1); atomicAdd(&c[d.y / NPB], 1);
      atomicAdd(&c[d.z / NPB], 1); atomicAdd(&c[d.w / NPB], 1);
    } else {
      for (int e = i; e < E; ++e) atomicAdd(&c[dst[e] / NPB], 1);
    }
  }
  __syncthreads();
  for (int t = tid; t < NBUCK; t += 256)
    if (c[t]) atomicAdd(&gcnt[t], c[t]);
}

// ---------------- bucket scan (1 block) ----------------
__global__ __launch_bounds__(512) void bscan_k(const int* __restrict__ gcnt,
                                               int* __restrict__ goff,
                                               int* __restrict__ gcur) {
  __shared__ int s[512];
  int t = threadIdx.x;
  int v = (t < NBUCK) ? gcnt[t] : 0;
  s[t] = v;
  __syncthreads();
  for (int d = 1; d < 512; d <<= 1) {
    int add = (t >= d) ? s[t - d] : 0;
    __syncthreads();
    s[t] += add;
    __syncthreads();
  }
  if (t < NBUCK) {
    int o = s[t] - v;          // exclusive
    goff[t] = o;
    gcur[t] = o;
    if (t == NBUCK - 1) goff[NBUCK] = s[t];
  }
}

// ---------------- bucketed scatter: edges -> bucket-grouped int2 pairs ----
__global__ __launch_bounds__(512) void bscatter_k(const int* __restrict__ src,
                                                  const int* __restrict__ dst,
                                                  int* __restrict__ gcur,
                                                  int2* __restrict__ pairs, int E) {
  __shared__ int lcnt[NBUCK];
  __shared__ int loff[NBUCK];
  __shared__ int lcur[NBUCK];
  __shared__ int lbase[NBUCK];
  __shared__ int s[512];
  __shared__ int s_src[TILE];
  __shared__ int s_dst[TILE];
  __shared__ int s_tgt[TILE];

  int tid = threadIdx.x;
  int tileStart = blockIdx.x * TILE;
  int tileCnt = E - tileStart; if (tileCnt > TILE) tileCnt = TILE;

  for (int t = tid; t < NBUCK; t += 512) lcnt[t] = 0;
  __syncthreads();

  // load up to 8 edges into registers
  int es[8], ed[8], eb[8];
  int base = tileStart + tid * 8;
  int ne = 0;
  if (base + 7 < E) {
    int4 a0 = *(const int4*)(src + base);
    int4 a1 = *(const int4*)(src + base + 4);
    int4 b0 = *(const int4*)(dst + base);
    int4 b1 = *(const int4*)(dst + base + 4);
    es[0]=a0.x; es[1]=a0.y; es[2]=a0.z; es[3]=a0.w;
    es[4]=a1.x; es[5]=a1.y; es[6]=a1.z; es[7]=a1.w;
    ed[0]=b0.x; ed[1]=b0.y; ed[2]=b0.z; ed[3]=b0.w;
    ed[4]=b1.x; ed[5]=b1.y; ed[6]=b1.z; ed[7]=b1.w;
    ne = 8;
  } else {
    for (int j = 0; j < 8 && base + j < E; ++j) {
      es[j] = src[base + j]; ed[j] = dst[base + j]; ++ne;
    }
  }
  for (int j = 0; j < ne; ++j) {
    eb[j] = ed[j] / NPB;
    atomicAdd(&lcnt[eb[j]], 1);
  }
  __syncthreads();

  // exclusive scan of lcnt (512-wide Hillis-Steele)
  int v = (tid < NBUCK) ? lcnt[tid] : 0;
  s[tid] = v;
  __syncthreads();
  for (int d = 1; d < 512; d <<= 1) {
    int add = (tid >= d) ? s[tid - d] : 0;
    __syncthreads();
    s[tid] += add;
    __syncthreads();
  }
  if (tid < NBUCK) {
    int o = s[tid] - v;
    loff[tid] = o;
    lcur[tid] = o;
    if (v) lbase[tid] = atomicAdd(&gcur[tid], v);
  }
  __syncthreads();

  // group edges by bucket into LDS staging, computing global target slots
  for (int j = 0; j < ne; ++j) {
    int b = eb[j];
    int slot = atomicAdd(&lcur[b], 1);
    s_src[slot] = es[j];
    s_dst[slot] = ed[j];
    s_tgt[slot] = lbase[b] + (slot - loff[b]);
  }
  __syncthreads();

  // flush: consecutive slots in a bucket -> consecutive global addrs
  for (int k = tid; k < tileCnt; k += 512) {
    pairs[s_tgt[k]] = make_int2(s_src[k], s_dst[k]);
  }
}

// ---------------- regroup: bucket-grouped pairs -> node-sorted CSR ----------
// One block per bucket. All global writes coalesced.
__global__ __launch_bounds__(256) void regroup_k(const int* __restrict__ goff,
                                                 const int2* __restrict__ pairs,
                                                 int* __restrict__ csr,
                                                 int* __restrict__ off,
                                                 int* __restrict__ cnt,
                                                 float* __restrict__ inv, int n) {
  __shared__ int lcnt[NPB];
  __shared__ int lofs[NPB];
  __shared__ int lcur[NPB];
  __shared__ int s[256];
  __shared__ int stage[CAP];

  int tid = threadIdx.x;
  int b = blockIdx.x;
  int nbase = b * NPB;
  int nn = n - nbase; if (nn > NPB) nn = NPB;
  if (nn <= 0) return;

  int e0 = goff[b], e1 = goff[b + 1];
  int m = e1 - e0;

  for (int t = tid; t < NPB; t += 256) lcnt[t] = 0;
  __syncthreads();

  // pass 1: per-node counts
  for (int e = e0 + tid; e < e1; e += 256)
    atomicAdd(&lcnt[pairs[e].y - nbase], 1);
  __syncthreads();

  // exclusive scan of 200 counts
  int v = (tid < NPB) ? lcnt[tid] : 0;
  s[tid] = v;
  __syncthreads();
  for (int d = 1; d < 256; d <<= 1) {
    int add = (tid >= d) ? s[tid - d] : 0;
    __syncthreads();
    s[tid] += add;
    __syncthreads();
  }
  if (tid < NPB) { int o = s[tid] - v; lofs[tid] = o; lcur[tid] = o; }
  __syncthreads();

  // pass 2: scatter src into LDS staging (random-in-LDS is cheap)
  for (int e = e0 + tid; e < e1; e += 256) {
    int2 p = pairs[e];
    int slot = atomicAdd(&lcur[p.y - nbase], 1);
    if (slot < CAP) stage[slot] = p.x;
    else csr[e0 + slot] = p.x;       // overflow fallback (correct, slow)
  }
  __syncthreads();

  // coalesced CSR flush + per-node metadata
  int mm = m < CAP ? m : CAP;
  for (int k = tid; k < mm; k += 256) csr[e0 + k] = stage[k];
  for (int t = tid; t < nn; t += 256) {
    int c = lcnt[t];
    cnt[nbase + t] = c;
    off[nbase + t] = e0 + lofs[t];
    inv[nbase + t] = 1.0f / (float)(c > 1 ? c : 1);
  }
}

// ---------------- Dense GEMM: Z = X@Wl^T, P = X@Wr^T + b ----------------
__global__ __launch_bounds__(256) void gemm_k(const float* __restrict__ X,
                                              const float* __restrict__ Wl,
                                              const float* __restrict__ Wr,
                                              const float* __restrict__ b,
                                              float* __restrict__ Z,
                                              float* __restrict__ P, int n) {
  __shared__ float sWl[64 * 64];   // transposed: sWl[k*64+o] = Wl[o][k]
  __shared__ float sWr[64 * 64];
  __shared__ float sb[64];
  __shared__ float sx[4 * GR * 64];

  int tid = threadIdx.x;
  for (int idx = tid; idx < 4096; idx += 256) {
    int k = idx >> 6, o = idx & 63;
    sWl[k * 64 + o] = Wl[o * 64 + k];
    sWr[k * 64 + o] = Wr[o * 64 + k];
  }
  if (tid < 64) sb[tid] = b[tid];

  int wave = tid >> 6;
  int lane = tid & 63;
  int row0 = (blockIdx.x * 4 + wave) * GR;

  if (row0 + GR <= n) {
    const float4* xs = (const float4*)(X + (size_t)row0 * NFEAT);
    float4* sxw = (float4*)(sx + wave * (GR * 64));
    sxw[lane] = xs[lane];
    sxw[lane + 64] = xs[lane + 64];
  } else if (row0 < n) {
    for (int j = 0; j < GR; ++j) {
      if (row0 + j < n) sx[wave * (GR * 64) + j * 64 + lane] = X[(size_t)(row0 + j) * NFEAT + lane];
    }
  }
  __syncthreads();
  if (row0 >= n) return;

  float accz[GR], accp[GR];
#pragma unroll
  for (int j = 0; j < GR; ++j) { accz[j] = 0.0f; accp[j] = sb[lane]; }

  const float* xw = sx + wave * (GR * 64);
#pragma unroll 2
  for (int kk = 0; kk < 64; kk += 4) {
    float wl0 = sWl[(kk + 0) * 64 + lane];
    float wl1 = sWl[(kk + 1) * 64 + lane];
    float wl2 = sWl[(kk + 2) * 64 + lane];
    float wl3 = sWl[(kk + 3) * 64 + lane];
    float wr0 = sWr[(kk + 0) * 64 + lane];
    float wr1 = sWr[(kk + 1) * 64 + lane];
    float wr2 = sWr[(kk + 2) * 64 + lane];
    float wr3 = sWr[(kk + 3) * 64 + lane];
#pragma unroll
    for (int j = 0; j < GR; ++j) {
      float4 xk = *(const float4*)&xw[j * 64 + kk];
      accz[j] += xk.x * wl0 + xk.y * wl1 + xk.z * wl2 + xk.w * wl3;
      accp[j] += xk.x * wr0 + xk.y * wr1 + xk.z * wr2 + xk.w * wr3;
    }
  }

#pragma unroll
  for (int j = 0; j < GR; ++j) {
    int r = row0 + j;
    if (r < n) {
      Z[(size_t)r * NFEAT + lane] = accz[j];
      P[(size_t)r * NFEAT + lane] = accp[j];
    }
  }
}

// ---------------- CSR gather-mean + epilogue (R2, known-good) ----------------
__global__ __launch_bounds__(256) void agg_k(const int* __restrict__ off,
                                             const int* __restrict__ cnt,
                                             const float* __restrict__ inv,
                                             const int* __restrict__ csr,
                                             const float* __restrict__ Z,
                                             const float* __restrict__ Pin,
                                             float* __restrict__ out, int n) {
  int node = (blockIdx.x * 256 + threadIdx.x) >> 6;
  if (node >= n) return;
  int lane = threadIdx.x & 63;
  int g = lane >> 4;
  int q = lane & 15;

  int start = off[node];
  int deg = cnt[node];

  float ax = 0.f, ay = 0.f, az = 0.f, aw = 0.f;
  for (int j = g; j < deg; j += 4) {
    int nb = csr[start + j];
    float4 v = *(const float4*)&Z[(size_t)nb * NFEAT + q * 4];
    ax += v.x; ay += v.y; az += v.z; aw += v.w;
  }

  ax += __shfl_xor(ax, 16); ay += __shfl_xor(ay, 16);
  az += __shfl_xor(az, 16); aw += __shfl_xor(aw, 16);
  ax += __shfl_xor(ax, 32); ay += __shfl_xor(ay, 32);
  az += __shfl_xor(az, 32); aw += __shfl_xor(aw, 32);

  if (g == 0) {
    float iv = inv[node];
    float4 p = *(const float4*)&Pin[(size_t)node * NFEAT + q * 4];
    float4 r;
    r.x = fmaxf(ax * iv + p.x, 0.f);
    r.y = fmaxf(ay * iv + p.y, 0.f);
    r.z = fmaxf(az * iv + p.z, 0.f);
    r.w = fmaxf(aw * iv + p.w, 0.f);
    *(float4*)&out[(size_t)node * NFEAT + q * 4] = r;
  }
}

// ---------------- launcher ----------------
extern "C" void kernel_launch(void* const* d_in, const int* in_sizes, int n_in,
                              void* d_out, int out_size, void* d_ws, size_t ws_size,
                              hipStream_t stream) {
  const float* x   = (const float*)d_in[0];
  const int*   ei  = (const int*)d_in[1];
  const float* W1l = (const float*)d_in[2];
  const float* b1  = (const float*)d_in[3];
  const float* W1r = (const float*)d_in[4];
  const float* W2l = (const float*)d_in[5];
  const float* b2  = (const float*)d_in[6];
  const float* W2r = (const float*)d_in[7];
  float* out = (float*)d_out;

  int N = in_sizes[0] / NFEAT;     // 100000
  int E = in_sizes[1] / 2;         // 1600000
  const int* srcp = ei;
  const int* dstp = ei + E;

  char* w = (char*)d_ws;
  int2*  pairs = (int2*)w;  w += (size_t)E * 8;
  int*   csr   = (int*)w;   w += (size_t)E * 4;
  float* Z     = (float*)w; w += (size_t)N * NFEAT * 4;
  float* H     = (float*)w; w += (size_t)N * NFEAT * 4;
  int*   off   = (int*)w;   w += (size_t)N * 4;
  int*   cnt   = (int*)w;   w += (size_t)N * 4;
  float* inv   = (float*)w; w += (size_t)N * 4;
  int*   gcnt  = (int*)w;   w += NBUCK * 4;
  int*   goff  = (int*)w;   w += (NBUCK + 1) * 4;
  int*   gcur  = (int*)w;   w += NBUCK * 4;
  if ((size_t)(w - (char*)d_ws) > ws_size) return;

  hipMemsetAsync(gcnt, 0, NBUCK * 4, stream);

  bcount_k<<<256, 256, 0, stream>>>(dstp, gcnt, E);
  bscan_k<<<1, 512, 0, stream>>>(gcnt, goff, gcur);
  int sb = (E + TILE - 1) / TILE;
  bscatter_k<<<sb, 512, 0, stream>>>(srcp, dstp, gcur, pairs, E);
  regroup_k<<<NBUCK, 256, 0, stream>>>(goff, pairs, csr, off, cnt, inv, N);

  int gb = (N + 4 * GR - 1) / (4 * GR);
  int ab = (N + 3) / 4;

  // layer 1: Z = x@W1l^T ; P = x@W1r^T + b1 -> d_out ; H = relu(agg + P)
  gemm_k<<<gb, 256, 0, stream>>>(x, W1l, W1r, b1, Z, out, N);
  agg_k<<<ab, 256, 0, stream>>>(off, cnt, inv, csr, Z, out, H, N);
  // layer 2 (row-wise in-place on d_out is safe)
  gemm_k<<<gb, 256, 0, stream>>>(H, W2l, W2r, b2, Z, out, N);
  agg_k<<<ab, 256, 0, stream>>>(off, cnt, inv, csr, Z, out, out, N);
}

// Round 5
// 303.738 us; speedup vs baseline: 4.3734x; 1.2814x over previous
//
#include <hip/hip_runtime.h>
#include <hip/hip_fp16.h>

// GraphSAGE 2-layer, N=100000 nodes, d=64, E=1.6M edges, fp32.
// per layer: out = relu( (scatter_sum(x)@Wl^T) * inv_cnt + b + x@Wr^T )
//   = dense GEMM (Z = X@Wl^T fp16, P = X@Wr^T + b fp32) + CSR gather-mean.
// CSR built via two-level coalesced scatter (bcount/bscan/bscatter/regroup).
// R5: (a) Z stored fp16 -> random gather rows 256B->128B (agg was
// line-rate bound: 6.4M lines/70us); (b) gemm weight reads b128 from
// stride-68 row-major LDS (2 reads/step vs 8 b32; R1's spill was the full
// unroll, not this layout -- keep unroll 2).

#define NFEAT 64
#define GR 8        // rows per wave in GEMM
#define NPB 200     // nodes per bucket
#define NBUCK 500   // ceil(100000/200)
#define TILE 4096   // edges per bscatter block (512 thr x 8)
#define CAP 4608    // regroup LDS staging (bucket mean 3200, ~15 sigma margin)

// ---------------- bucket count ----------------
__global__ __launch_bounds__(256) void bcount_k(const int* __restrict__ dst,
                                                int* __restrict__ gcnt, int E) {
  __shared__ int c[NBUCK];
  int tid = threadIdx.x;
  for (int t = tid; t < NBUCK; t += 256) c[t] = 0;
  __syncthreads();
  int stride = gridDim.x * 256 * 4;
  for (int i = (blockIdx.x * 256 + tid) * 4; i < E; i += stride) {
    if (i + 3 < E) {
      int4 d = *(const int4*)(dst + i);
      atomicAdd(&c[d.x / NPB], 1); atomicAdd(&c[d.y / NPB], 1);
      atomicAdd(&c[d.z / NPB], 1); atomicAdd(&c[d.w / NPB], 1);
    } else {
      for (int e = i; e < E; ++e) atomicAdd(&c[dst[e] / NPB], 1);
    }
  }
  __syncthreads();
  for (int t = tid; t < NBUCK; t += 256)
    if (c[t]) atomicAdd(&gcnt[t], c[t]);
}

// ---------------- bucket scan (1 block) ----------------
__global__ __launch_bounds__(512) void bscan_k(const int* __restrict__ gcnt,
                                               int* __restrict__ goff,
                                               int* __restrict__ gcur) {
  __shared__ int s[512];
  int t = threadIdx.x;
  int v = (t < NBUCK) ? gcnt[t] : 0;
  s[t] = v;
  __syncthreads();
  for (int d = 1; d < 512; d <<= 1) {
    int add = (t >= d) ? s[t - d] : 0;
    __syncthreads();
    s[t] += add;
    __syncthreads();
  }
  if (t < NBUCK) {
    int o = s[t] - v;          // exclusive
    goff[t] = o;
    gcur[t] = o;
    if (t == NBUCK - 1) goff[NBUCK] = s[t];
  }
}

// ---------------- bucketed scatter: edges -> bucket-grouped int2 pairs ----
__global__ __launch_bounds__(512) void bscatter_k(const int* __restrict__ src,
                                                  const int* __restrict__ dst,
                                                  int* __restrict__ gcur,
                                                  int2* __restrict__ pairs, int E) {
  __shared__ int lcnt[NBUCK];
  __shared__ int loff[NBUCK];
  __shared__ int lcur[NBUCK];
  __shared__ int lbase[NBUCK];
  __shared__ int s[512];
  __shared__ int s_src[TILE];
  __shared__ int s_dst[TILE];
  __shared__ int s_tgt[TILE];

  int tid = threadIdx.x;
  int tileStart = blockIdx.x * TILE;
  int tileCnt = E - tileStart; if (tileCnt > TILE) tileCnt = TILE;

  for (int t = tid; t < NBUCK; t += 512) lcnt[t] = 0;
  __syncthreads();

  int es[8], ed[8], eb[8];
  int base = tileStart + tid * 8;
  int ne = 0;
  if (base + 7 < E) {
    int4 a0 = *(const int4*)(src + base);
    int4 a1 = *(const int4*)(src + base + 4);
    int4 b0 = *(const int4*)(dst + base);
    int4 b1 = *(const int4*)(dst + base + 4);
    es[0]=a0.x; es[1]=a0.y; es[2]=a0.z; es[3]=a0.w;
    es[4]=a1.x; es[5]=a1.y; es[6]=a1.z; es[7]=a1.w;
    ed[0]=b0.x; ed[1]=b0.y; ed[2]=b0.z; ed[3]=b0.w;
    ed[4]=b1.x; ed[5]=b1.y; ed[6]=b1.z; ed[7]=b1.w;
    ne = 8;
  } else {
    for (int j = 0; j < 8 && base + j < E; ++j) {
      es[j] = src[base + j]; ed[j] = dst[base + j]; ++ne;
    }
  }
  for (int j = 0; j < ne; ++j) {
    eb[j] = ed[j] / NPB;
    atomicAdd(&lcnt[eb[j]], 1);
  }
  __syncthreads();

  int v = (tid < NBUCK) ? lcnt[tid] : 0;
  s[tid] = v;
  __syncthreads();
  for (int d = 1; d < 512; d <<= 1) {
    int add = (tid >= d) ? s[tid - d] : 0;
    __syncthreads();
    s[tid] += add;
    __syncthreads();
  }
  if (tid < NBUCK) {
    int o = s[tid] - v;
    loff[tid] = o;
    lcur[tid] = o;
    if (v) lbase[tid] = atomicAdd(&gcur[tid], v);
  }
  __syncthreads();

  for (int j = 0; j < ne; ++j) {
    int b = eb[j];
    int slot = atomicAdd(&lcur[b], 1);
    s_src[slot] = es[j];
    s_dst[slot] = ed[j];
    s_tgt[slot] = lbase[b] + (slot - loff[b]);
  }
  __syncthreads();

  for (int k = tid; k < tileCnt; k += 512) {
    pairs[s_tgt[k]] = make_int2(s_src[k], s_dst[k]);
  }
}

// ---------------- regroup: bucket-grouped pairs -> node-sorted CSR ----------
__global__ __launch_bounds__(256) void regroup_k(const int* __restrict__ goff,
                                                 const int2* __restrict__ pairs,
                                                 int* __restrict__ csr,
                                                 int* __restrict__ off,
                                                 int* __restrict__ cnt,
                                                 float* __restrict__ inv, int n) {
  __shared__ int lcnt[NPB];
  __shared__ int lofs[NPB];
  __shared__ int lcur[NPB];
  __shared__ int s[256];
  __shared__ int stage[CAP];

  int tid = threadIdx.x;
  int b = blockIdx.x;
  int nbase = b * NPB;
  int nn = n - nbase; if (nn > NPB) nn = NPB;
  if (nn <= 0) return;

  int e0 = goff[b], e1 = goff[b + 1];
  int m = e1 - e0;

  for (int t = tid; t < NPB; t += 256) lcnt[t] = 0;
  __syncthreads();

  for (int e = e0 + tid; e < e1; e += 256)
    atomicAdd(&lcnt[pairs[e].y - nbase], 1);
  __syncthreads();

  int v = (tid < NPB) ? lcnt[tid] : 0;
  s[tid] = v;
  __syncthreads();
  for (int d = 1; d < 256; d <<= 1) {
    int add = (tid >= d) ? s[tid - d] : 0;
    __syncthreads();
    s[tid] += add;
    __syncthreads();
  }
  if (tid < NPB) { int o = s[tid] - v; lofs[tid] = o; lcur[tid] = o; }
  __syncthreads();

  for (int e = e0 + tid; e < e1; e += 256) {
    int2 p = pairs[e];
    int slot = atomicAdd(&lcur[p.y - nbase], 1);
    if (slot < CAP) stage[slot] = p.x;
    else csr[e0 + slot] = p.x;       // overflow fallback (correct, slow)
  }
  __syncthreads();

  int mm = m < CAP ? m : CAP;
  for (int k = tid; k < mm; k += 256) csr[e0 + k] = stage[k];
  for (int t = tid; t < nn; t += 256) {
    int c = lcnt[t];
    cnt[nbase + t] = c;
    off[nbase + t] = e0 + lofs[t];
    inv[nbase + t] = 1.0f / (float)(c > 1 ? c : 1);
  }
}

// ---------------- Dense GEMM: Zh = fp16(X@Wl^T), P = X@Wr^T + b ----------------
// Weights row-major in LDS, stride 68 (16B-aligned, 8-lane b128 phases tile
// all 32 banks). 2 b128 weight reads + 8 uniform b128 x reads per kk-step.
__global__ __launch_bounds__(256) void gemm_k(const float* __restrict__ X,
                                              const float* __restrict__ Wl,
                                              const float* __restrict__ Wr,
                                              const float* __restrict__ b,
                                              __half* __restrict__ Zh,
                                              float* __restrict__ P, int n) {
  __shared__ float sWl[64 * 68];   // sWl[o*68+k] = Wl[o][k]
  __shared__ float sWr[64 * 68];
  __shared__ float sb[64];
  __shared__ float sx[4 * GR * 64];

  int tid = threadIdx.x;
  for (int idx = tid; idx < 4096; idx += 256) {
    int o = idx >> 6, k = idx & 63;
    sWl[o * 68 + k] = Wl[idx];
    sWr[o * 68 + k] = Wr[idx];
  }
  if (tid < 64) sb[tid] = b[tid];

  int wave = tid >> 6;
  int lane = tid & 63;
  int row0 = (blockIdx.x * 4 + wave) * GR;

  if (row0 + GR <= n) {
    const float4* xs = (const float4*)(X + (size_t)row0 * NFEAT);
    float4* sxw = (float4*)(sx + wave * (GR * 64));
    sxw[lane] = xs[lane];
    sxw[lane + 64] = xs[lane + 64];
  } else if (row0 < n) {
    for (int j = 0; j < GR; ++j) {
      if (row0 + j < n) sx[wave * (GR * 64) + j * 64 + lane] = X[(size_t)(row0 + j) * NFEAT + lane];
    }
  }
  __syncthreads();
  if (row0 >= n) return;

  float accz[GR], accp[GR];
#pragma unroll
  for (int j = 0; j < GR; ++j) { accz[j] = 0.0f; accp[j] = sb[lane]; }

  const float* xw = sx + wave * (GR * 64);
#pragma unroll 2
  for (int kk = 0; kk < 64; kk += 4) {
    float4 wl = *(const float4*)&sWl[lane * 68 + kk];
    float4 wr = *(const float4*)&sWr[lane * 68 + kk];
#pragma unroll
    for (int j = 0; j < GR; ++j) {
      float4 xk = *(const float4*)&xw[j * 64 + kk];   // wave-uniform broadcast
      accz[j] += xk.x * wl.x + xk.y * wl.y + xk.z * wl.z + xk.w * wl.w;
      accp[j] += xk.x * wr.x + xk.y * wr.y + xk.z * wr.z + xk.w * wr.w;
    }
  }

#pragma unroll
  for (int j = 0; j < GR; ++j) {
    int r = row0 + j;
    if (r < n) {
      Zh[(size_t)r * NFEAT + lane] = __float2half(accz[j]);
      P[(size_t)r * NFEAT + lane] = accp[j];
    }
  }
}

// ---------------- CSR gather-mean + epilogue (fp16 Z rows, 128B) ----------------
// One wave per node; 8 teams of 8 lanes; each team pulls one neighbor row
// (8 lanes x 16B = 128B), fp32 accumulate, xor-shuffle reduce across teams.
__device__ inline float2 h2f(unsigned u) {
  __half2 h = *reinterpret_cast<__half2*>(&u);
  return __half22float2(h);
}

__global__ __launch_bounds__(256) void agg_k(const int* __restrict__ off,
                                             const int* __restrict__ cnt,
                                             const float* __restrict__ inv,
                                             const int* __restrict__ csr,
                                             const __half* __restrict__ Z,
                                             const float* __restrict__ Pin,
                                             float* __restrict__ out, int n) {
  int node = (blockIdx.x * 256 + threadIdx.x) >> 6;
  if (node >= n) return;
  int lane = threadIdx.x & 63;
  int g = lane >> 3;   // 8 teams
  int q = lane & 7;

  int start = off[node];
  int deg = cnt[node];

  float a0=0.f,a1=0.f,a2=0.f,a3=0.f,a4=0.f,a5=0.f,a6=0.f,a7=0.f;
  for (int j = g; j < deg; j += 8) {
    int nb = csr[start + j];
    uint4 raw = *(const uint4*)(Z + (size_t)nb * NFEAT + q * 8);
    float2 f0 = h2f(raw.x), f1 = h2f(raw.y), f2 = h2f(raw.z), f3 = h2f(raw.w);
    a0 += f0.x; a1 += f0.y; a2 += f1.x; a3 += f1.y;
    a4 += f2.x; a5 += f2.y; a6 += f3.x; a7 += f3.y;
  }

  a0 += __shfl_xor(a0, 8);  a1 += __shfl_xor(a1, 8);
  a2 += __shfl_xor(a2, 8);  a3 += __shfl_xor(a3, 8);
  a4 += __shfl_xor(a4, 8);  a5 += __shfl_xor(a5, 8);
  a6 += __shfl_xor(a6, 8);  a7 += __shfl_xor(a7, 8);
  a0 += __shfl_xor(a0, 16); a1 += __shfl_xor(a1, 16);
  a2 += __shfl_xor(a2, 16); a3 += __shfl_xor(a3, 16);
  a4 += __shfl_xor(a4, 16); a5 += __shfl_xor(a5, 16);
  a6 += __shfl_xor(a6, 16); a7 += __shfl_xor(a7, 16);
  a0 += __shfl_xor(a0, 32); a1 += __shfl_xor(a1, 32);
  a2 += __shfl_xor(a2, 32); a3 += __shfl_xor(a3, 32);
  a4 += __shfl_xor(a4, 32); a5 += __shfl_xor(a5, 32);
  a6 += __shfl_xor(a6, 32); a7 += __shfl_xor(a7, 32);

  if (g == 0) {
    float iv = inv[node];
    const float* pp = &Pin[(size_t)node * NFEAT + q * 8];
    float4 p0 = *(const float4*)(pp);
    float4 p1 = *(const float4*)(pp + 4);
    float4 r0, r1;
    r0.x = fmaxf(a0 * iv + p0.x, 0.f);
    r0.y = fmaxf(a1 * iv + p0.y, 0.f);
    r0.z = fmaxf(a2 * iv + p0.z, 0.f);
    r0.w = fmaxf(a3 * iv + p0.w, 0.f);
    r1.x = fmaxf(a4 * iv + p1.x, 0.f);
    r1.y = fmaxf(a5 * iv + p1.y, 0.f);
    r1.z = fmaxf(a6 * iv + p1.z, 0.f);
    r1.w = fmaxf(a7 * iv + p1.w, 0.f);
    float* op = &out[(size_t)node * NFEAT + q * 8];
    *(float4*)(op) = r0;
    *(float4*)(op + 4) = r1;
  }
}

// ---------------- launcher ----------------
extern "C" void kernel_launch(void* const* d_in, const int* in_sizes, int n_in,
                              void* d_out, int out_size, void* d_ws, size_t ws_size,
                              hipStream_t stream) {
  const float* x   = (const float*)d_in[0];
  const int*   ei  = (const int*)d_in[1];
  const float* W1l = (const float*)d_in[2];
  const float* b1  = (const float*)d_in[3];
  const float* W1r = (const float*)d_in[4];
  const float* W2l = (const float*)d_in[5];
  const float* b2  = (const float*)d_in[6];
  const float* W2r = (const float*)d_in[7];
  float* out = (float*)d_out;

  int N = in_sizes[0] / NFEAT;     // 100000
  int E = in_sizes[1] / 2;         // 1600000
  const int* srcp = ei;
  const int* dstp = ei + E;

  char* w = (char*)d_ws;
  int2*   pairs = (int2*)w;   w += (size_t)E * 8;
  int*    csr   = (int*)w;    w += (size_t)E * 4;
  __half* Zh    = (__half*)w; w += (size_t)N * NFEAT * 2;
  float*  P     = (float*)w;  w += (size_t)N * NFEAT * 4;
  float*  H     = (float*)w;  w += (size_t)N * NFEAT * 4;
  int*    off   = (int*)w;    w += (size_t)N * 4;
  int*    cnt   = (int*)w;    w += (size_t)N * 4;
  float*  inv   = (float*)w;  w += (size_t)N * 4;
  int*    gcnt  = (int*)w;    w += NBUCK * 4;
  int*    goff  = (int*)w;    w += (NBUCK + 1) * 4;
  int*    gcur  = (int*)w;    w += NBUCK * 4;
  if ((size_t)(w - (char*)d_ws) > ws_size) return;

  hipMemsetAsync(gcnt, 0, NBUCK * 4, stream);

  bcount_k<<<256, 256, 0, stream>>>(dstp, gcnt, E);
  bscan_k<<<1, 512, 0, stream>>>(gcnt, goff, gcur);
  int sb = (E + TILE - 1) / TILE;
  bscatter_k<<<sb, 512, 0, stream>>>(srcp, dstp, gcur, pairs, E);
  regroup_k<<<NBUCK, 256, 0, stream>>>(goff, pairs, csr, off, cnt, inv, N);

  int gb = (N + 4 * GR - 1) / (4 * GR);
  int ab = (N + 3) / 4;

  // layer 1: Zh = fp16(x@W1l^T) ; P = x@W1r^T + b1 ; H = relu(agg + P)
  gemm_k<<<gb, 256, 0, stream>>>(x, W1l, W1r, b1, Zh, P, N);
  agg_k<<<ab, 256, 0, stream>>>(off, cnt, inv, csr, Zh, P, H, N);
  // layer 2 -> d_out
  gemm_k<<<gb, 256, 0, stream>>>(H, W2l, W2r, b2, Zh, P, N);
  agg_k<<<ab, 256, 0, stream>>>(off, cnt, inv, csr, Zh, P, out, N);
}

// Round 6
// 287.383 us; speedup vs baseline: 4.6223x; 1.0569x over previous
//
#include <hip/hip_runtime.h>
#include <hip/hip_fp16.h>

// GraphSAGE 2-layer, N=100000 nodes, d=64, E=1.6M edges, fp32.
// per layer: out = relu( (scatter_sum(x)@Wl^T) * inv_cnt + b + x@Wr^T )
//   = dense GEMM (Zh = fp16(X@Wl^T), Ph = fp16(X@Wr^T + b)) + CSR gather-mean.
// CSR built via two-level coalesced scatter (bcount/bscan/bscatter/regroup).
// R6: agg restructured team-per-node (8 lanes/node, no cross-lane reduction --
// the 48-instr xor-shuffle per node was ~30% of agg cycles); P stored fp16.

#define NFEAT 64
#define GR 8        // rows per wave in GEMM
#define NPB 200     // nodes per bucket
#define NBUCK 500   // ceil(100000/200)
#define TILE 4096   // edges per bscatter block (512 thr x 8)
#define CAP 4608    // regroup LDS staging (bucket mean 3200, ~15 sigma margin)

// ---------------- bucket count ----------------
__global__ __launch_bounds__(256) void bcount_k(const int* __restrict__ dst,
                                                int* __restrict__ gcnt, int E) {
  __shared__ int c[NBUCK];
  int tid = threadIdx.x;
  for (int t = tid; t < NBUCK; t += 256) c[t] = 0;
  __syncthreads();
  int stride = gridDim.x * 256 * 4;
  for (int i = (blockIdx.x * 256 + tid) * 4; i < E; i += stride) {
    if (i + 3 < E) {
      int4 d = *(const int4*)(dst + i);
      atomicAdd(&c[d.x / NPB], 1); atomicAdd(&c[d.y / NPB], 1);
      atomicAdd(&c[d.z / NPB], 1); atomicAdd(&c[d.w / NPB], 1);
    } else {
      for (int e = i; e < E; ++e) atomicAdd(&c[dst[e] / NPB], 1);
    }
  }
  __syncthreads();
  for (int t = tid; t < NBUCK; t += 256)
    if (c[t]) atomicAdd(&gcnt[t], c[t]);
}

// ---------------- bucket scan (1 block) ----------------
__global__ __launch_bounds__(512) void bscan_k(const int* __restrict__ gcnt,
                                               int* __restrict__ goff,
                                               int* __restrict__ gcur) {
  __shared__ int s[512];
  int t = threadIdx.x;
  int v = (t < NBUCK) ? gcnt[t] : 0;
  s[t] = v;
  __syncthreads();
  for (int d = 1; d < 512; d <<= 1) {
    int add = (t >= d) ? s[t - d] : 0;
    __syncthreads();
    s[t] += add;
    __syncthreads();
  }
  if (t < NBUCK) {
    int o = s[t] - v;          // exclusive
    goff[t] = o;
    gcur[t] = o;
    if (t == NBUCK - 1) goff[NBUCK] = s[t];
  }
}

// ---------------- bucketed scatter: edges -> bucket-grouped int2 pairs ----
__global__ __launch_bounds__(512) void bscatter_k(const int* __restrict__ src,
                                                  const int* __restrict__ dst,
                                                  int* __restrict__ gcur,
                                                  int2* __restrict__ pairs, int E) {
  __shared__ int lcnt[NBUCK];
  __shared__ int loff[NBUCK];
  __shared__ int lcur[NBUCK];
  __shared__ int lbase[NBUCK];
  __shared__ int s[512];
  __shared__ int s_src[TILE];
  __shared__ int s_dst[TILE];
  __shared__ int s_tgt[TILE];

  int tid = threadIdx.x;
  int tileStart = blockIdx.x * TILE;
  int tileCnt = E - tileStart; if (tileCnt > TILE) tileCnt = TILE;

  for (int t = tid; t < NBUCK; t += 512) lcnt[t] = 0;
  __syncthreads();

  int es[8], ed[8], eb[8];
  int base = tileStart + tid * 8;
  int ne = 0;
  if (base + 7 < E) {
    int4 a0 = *(const int4*)(src + base);
    int4 a1 = *(const int4*)(src + base + 4);
    int4 b0 = *(const int4*)(dst + base);
    int4 b1 = *(const int4*)(dst + base + 4);
    es[0]=a0.x; es[1]=a0.y; es[2]=a0.z; es[3]=a0.w;
    es[4]=a1.x; es[5]=a1.y; es[6]=a1.z; es[7]=a1.w;
    ed[0]=b0.x; ed[1]=b0.y; ed[2]=b0.z; ed[3]=b0.w;
    ed[4]=b1.x; ed[5]=b1.y; ed[6]=b1.z; ed[7]=b1.w;
    ne = 8;
  } else {
    for (int j = 0; j < 8 && base + j < E; ++j) {
      es[j] = src[base + j]; ed[j] = dst[base + j]; ++ne;
    }
  }
  for (int j = 0; j < ne; ++j) {
    eb[j] = ed[j] / NPB;
    atomicAdd(&lcnt[eb[j]], 1);
  }
  __syncthreads();

  int v = (tid < NBUCK) ? lcnt[tid] : 0;
  s[tid] = v;
  __syncthreads();
  for (int d = 1; d < 512; d <<= 1) {
    int add = (tid >= d) ? s[tid - d] : 0;
    __syncthreads();
    s[tid] += add;
    __syncthreads();
  }
  if (tid < NBUCK) {
    int o = s[tid] - v;
    loff[tid] = o;
    lcur[tid] = o;
    if (v) lbase[tid] = atomicAdd(&gcur[tid], v);
  }
  __syncthreads();

  for (int j = 0; j < ne; ++j) {
    int b = eb[j];
    int slot = atomicAdd(&lcur[b], 1);
    s_src[slot] = es[j];
    s_dst[slot] = ed[j];
    s_tgt[slot] = lbase[b] + (slot - loff[b]);
  }
  __syncthreads();

  for (int k = tid; k < tileCnt; k += 512) {
    pairs[s_tgt[k]] = make_int2(s_src[k], s_dst[k]);
  }
}

// ---------------- regroup: bucket-grouped pairs -> node-sorted CSR ----------
__global__ __launch_bounds__(256) void regroup_k(const int* __restrict__ goff,
                                                 const int2* __restrict__ pairs,
                                                 int* __restrict__ csr,
                                                 int* __restrict__ off,
                                                 int* __restrict__ cnt,
                                                 float* __restrict__ inv, int n) {
  __shared__ int lcnt[NPB];
  __shared__ int lofs[NPB];
  __shared__ int lcur[NPB];
  __shared__ int s[256];
  __shared__ int stage[CAP];

  int tid = threadIdx.x;
  int b = blockIdx.x;
  int nbase = b * NPB;
  int nn = n - nbase; if (nn > NPB) nn = NPB;
  if (nn <= 0) return;

  int e0 = goff[b], e1 = goff[b + 1];
  int m = e1 - e0;

  for (int t = tid; t < NPB; t += 256) lcnt[t] = 0;
  __syncthreads();

  for (int e = e0 + tid; e < e1; e += 256)
    atomicAdd(&lcnt[pairs[e].y - nbase], 1);
  __syncthreads();

  int v = (tid < NPB) ? lcnt[tid] : 0;
  s[tid] = v;
  __syncthreads();
  for (int d = 1; d < 256; d <<= 1) {
    int add = (tid >= d) ? s[tid - d] : 0;
    __syncthreads();
    s[tid] += add;
    __syncthreads();
  }
  if (tid < NPB) { int o = s[tid] - v; lofs[tid] = o; lcur[tid] = o; }
  __syncthreads();

  for (int e = e0 + tid; e < e1; e += 256) {
    int2 p = pairs[e];
    int slot = atomicAdd(&lcur[p.y - nbase], 1);
    if (slot < CAP) stage[slot] = p.x;
    else csr[e0 + slot] = p.x;       // overflow fallback (correct, slow)
  }
  __syncthreads();

  int mm = m < CAP ? m : CAP;
  for (int k = tid; k < mm; k += 256) csr[e0 + k] = stage[k];
  for (int t = tid; t < nn; t += 256) {
    int c = lcnt[t];
    cnt[nbase + t] = c;
    off[nbase + t] = e0 + lofs[t];
    inv[nbase + t] = 1.0f / (float)(c > 1 ? c : 1);
  }
}

// ---------------- Dense GEMM: Zh = fp16(X@Wl^T), Ph = fp16(X@Wr^T + b) ------
__global__ __launch_bounds__(256) void gemm_k(const float* __restrict__ X,
                                              const float* __restrict__ Wl,
                                              const float* __restrict__ Wr,
                                              const float* __restrict__ b,
                                              __half* __restrict__ Zh,
                                              __half* __restrict__ Ph, int n) {
  __shared__ float sWl[64 * 68];   // sWl[o*68+k] = Wl[o][k]
  __shared__ float sWr[64 * 68];
  __shared__ float sb[64];
  __shared__ float sx[4 * GR * 64];

  int tid = threadIdx.x;
  for (int idx = tid; idx < 4096; idx += 256) {
    int o = idx >> 6, k = idx & 63;
    sWl[o * 68 + k] = Wl[idx];
    sWr[o * 68 + k] = Wr[idx];
  }
  if (tid < 64) sb[tid] = b[tid];

  int wave = tid >> 6;
  int lane = tid & 63;
  int row0 = (blockIdx.x * 4 + wave) * GR;

  if (row0 + GR <= n) {
    const float4* xs = (const float4*)(X + (size_t)row0 * NFEAT);
    float4* sxw = (float4*)(sx + wave * (GR * 64));
    sxw[lane] = xs[lane];
    sxw[lane + 64] = xs[lane + 64];
  } else if (row0 < n) {
    for (int j = 0; j < GR; ++j) {
      if (row0 + j < n) sx[wave * (GR * 64) + j * 64 + lane] = X[(size_t)(row0 + j) * NFEAT + lane];
    }
  }
  __syncthreads();
  if (row0 >= n) return;

  float accz[GR], accp[GR];
#pragma unroll
  for (int j = 0; j < GR; ++j) { accz[j] = 0.0f; accp[j] = sb[lane]; }

  const float* xw = sx + wave * (GR * 64);
#pragma unroll 2
  for (int kk = 0; kk < 64; kk += 4) {
    float4 wl = *(const float4*)&sWl[lane * 68 + kk];
    float4 wr = *(const float4*)&sWr[lane * 68 + kk];
#pragma unroll
    for (int j = 0; j < GR; ++j) {
      float4 xk = *(const float4*)&xw[j * 64 + kk];   // wave-uniform broadcast
      accz[j] += xk.x * wl.x + xk.y * wl.y + xk.z * wl.z + xk.w * wl.w;
      accp[j] += xk.x * wr.x + xk.y * wr.y + xk.z * wr.z + xk.w * wr.w;
    }
  }

#pragma unroll
  for (int j = 0; j < GR; ++j) {
    int r = row0 + j;
    if (r < n) {
      Zh[(size_t)r * NFEAT + lane] = __float2half(accz[j]);
      Ph[(size_t)r * NFEAT + lane] = __float2half(accp[j]);
    }
  }
}

// ---------------- CSR gather-mean + epilogue (team-per-node) ----------------
// 8-lane team per node (8 nodes/wave). Each lane owns 8 features (16B of the
// 128B fp16 row) and accumulates privately across the node's whole neighbor
// list -> NO cross-lane reduction (R5's 48-instr shuffle per node was ~30% of
// agg cycles). Divergence cost: wave runs max(deg of its 8 nodes) iters.
__device__ inline float2 h2f(unsigned u) {
  __half2 h = *reinterpret_cast<__half2*>(&u);
  return __half22float2(h);
}

__global__ __launch_bounds__(256) void agg_k(const int* __restrict__ off,
                                             const int* __restrict__ cnt,
                                             const float* __restrict__ inv,
                                             const int* __restrict__ csr,
                                             const __half* __restrict__ Z,
                                             const __half* __restrict__ Pin,
                                             float* __restrict__ out, int n) {
  int t = blockIdx.x * 256 + threadIdx.x;
  int node = t >> 3;
  if (node >= n) return;
  int q = t & 7;            // feature octet owned by this lane

  int start = off[node];
  int deg = cnt[node];

  float a0=0.f,a1=0.f,a2=0.f,a3=0.f,a4=0.f,a5=0.f,a6=0.f,a7=0.f;
  for (int j = 0; j < deg; ++j) {
    int nb = csr[start + j];                       // team-uniform load
    uint4 raw = *(const uint4*)(Z + (size_t)nb * NFEAT + q * 8);
    float2 f0 = h2f(raw.x), f1 = h2f(raw.y), f2 = h2f(raw.z), f3 = h2f(raw.w);
    a0 += f0.x; a1 += f0.y; a2 += f1.x; a3 += f1.y;
    a4 += f2.x; a5 += f2.y; a6 += f3.x; a7 += f3.y;
  }

  float iv = inv[node];
  uint4 praw = *(const uint4*)(Pin + (size_t)node * NFEAT + q * 8);
  float2 p0 = h2f(praw.x), p1 = h2f(praw.y), p2 = h2f(praw.z), p3 = h2f(praw.w);
  float4 r0, r1;
  r0.x = fmaxf(a0 * iv + p0.x, 0.f);
  r0.y = fmaxf(a1 * iv + p0.y, 0.f);
  r0.z = fmaxf(a2 * iv + p1.x, 0.f);
  r0.w = fmaxf(a3 * iv + p1.y, 0.f);
  r1.x = fmaxf(a4 * iv + p2.x, 0.f);
  r1.y = fmaxf(a5 * iv + p2.y, 0.f);
  r1.z = fmaxf(a6 * iv + p3.x, 0.f);
  r1.w = fmaxf(a7 * iv + p3.y, 0.f);
  float* op = &out[(size_t)node * NFEAT + q * 8];
  *(float4*)(op) = r0;
  *(float4*)(op + 4) = r1;
}

// ---------------- launcher ----------------
extern "C" void kernel_launch(void* const* d_in, const int* in_sizes, int n_in,
                              void* d_out, int out_size, void* d_ws, size_t ws_size,
                              hipStream_t stream) {
  const float* x   = (const float*)d_in[0];
  const int*   ei  = (const int*)d_in[1];
  const float* W1l = (const float*)d_in[2];
  const float* b1  = (const float*)d_in[3];
  const float* W1r = (const float*)d_in[4];
  const float* W2l = (const float*)d_in[5];
  const float* b2  = (const float*)d_in[6];
  const float* W2r = (const float*)d_in[7];
  float* out = (float*)d_out;

  int N = in_sizes[0] / NFEAT;     // 100000
  int E = in_sizes[1] / 2;         // 1600000
  const int* srcp = ei;
  const int* dstp = ei + E;

  char* w = (char*)d_ws;
  int2*   pairs = (int2*)w;   w += (size_t)E * 8;
  int*    csr   = (int*)w;    w += (size_t)E * 4;
  __half* Zh    = (__half*)w; w += (size_t)N * NFEAT * 2;
  __half* Ph    = (__half*)w; w += (size_t)N * NFEAT * 2;
  float*  H     = (float*)w;  w += (size_t)N * NFEAT * 4;
  int*    off   = (int*)w;    w += (size_t)N * 4;
  int*    cnt   = (int*)w;    w += (size_t)N * 4;
  float*  inv   = (float*)w;  w += (size_t)N * 4;
  int*    gcnt  = (int*)w;    w += NBUCK * 4;
  int*    goff  = (int*)w;    w += (NBUCK + 1) * 4;
  int*    gcur  = (int*)w;    w += NBUCK * 4;
  if ((size_t)(w - (char*)d_ws) > ws_size) return;

  hipMemsetAsync(gcnt, 0, NBUCK * 4, stream);

  bcount_k<<<256, 256, 0, stream>>>(dstp, gcnt, E);
  bscan_k<<<1, 512, 0, stream>>>(gcnt, goff, gcur);
  int sb = (E + TILE - 1) / TILE;
  bscatter_k<<<sb, 512, 0, stream>>>(srcp, dstp, gcur, pairs, E);
  regroup_k<<<NBUCK, 256, 0, stream>>>(goff, pairs, csr, off, cnt, inv, N);

  int gb = (N + 4 * GR - 1) / (4 * GR);
  int ab = (N * 8 + 255) / 256;    // 8 lanes per node

  // layer 1: Zh = fp16(x@W1l^T) ; Ph = fp16(x@W1r^T + b1) ; H = relu(agg + P)
  gemm_k<<<gb, 256, 0, stream>>>(x, W1l, W1r, b1, Zh, Ph, N);
  agg_k<<<ab, 256, 0, stream>>>(off, cnt, inv, csr, Zh, Ph, H, N);
  // layer 2 -> d_out
  gemm_k<<<gb, 256, 0, stream>>>(H, W2l, W2r, b2, Zh, Ph, N);
  agg_k<<<ab, 256, 0, stream>>>(off, cnt, inv, csr, Zh, Ph, out, N);
}

// Round 7
// 284.711 us; speedup vs baseline: 4.6657x; 1.0094x over previous
//
#include <hip/hip_runtime.h>
#include <hip/hip_fp16.h>

// GraphSAGE 2-layer, N=100000 nodes, d=64, E=1.6M edges, fp32.
// per layer: out = relu( (scatter_sum(x)@Wl^T) * inv_cnt + b + x@Wr^T )
//   = MFMA GEMM (Zh = fp16(X@Wl^T), Ph = fp16(X@Wr^T + b)) + CSR gather-mean.
// CSR built via two-level coalesced scatter (bcount/bscan/bscatter/regroup).
// R7: gemm moved to v_mfma_f32_16x16x32_f16 (R6 gemm was VALU-issue bound:
// 60% VALUBusy, 48us vs 11us ideal). Operand-swap (A=W, B=X) so C-layout
// (col=lane&15=node, row=quad*4+reg=feature) yields per-lane contiguous
// 4-feature fp16 stores -- no LDS, no epilogue transpose.

#define NFEAT 64
#define NPB 200     // nodes per bucket
#define NBUCK 500   // ceil(100000/200)
#define TILE 4096   // edges per bscatter block (512 thr x 8)
#define CAP 4608    // regroup LDS staging (bucket mean 3200, ~15 sigma margin)

typedef _Float16 h8 __attribute__((ext_vector_type(8)));
typedef _Float16 h4 __attribute__((ext_vector_type(4)));
typedef float f4 __attribute__((ext_vector_type(4)));

// ---------------- bucket count ----------------
__global__ __launch_bounds__(256) void bcount_k(const int* __restrict__ dst,
                                                int* __restrict__ gcnt, int E) {
  __shared__ int c[NBUCK];
  int tid = threadIdx.x;
  for (int t = tid; t < NBUCK; t += 256) c[t] = 0;
  __syncthreads();
  int stride = gridDim.x * 256 * 4;
  for (int i = (blockIdx.x * 256 + tid) * 4; i < E; i += stride) {
    if (i + 3 < E) {
      int4 d = *(const int4*)(dst + i);
      atomicAdd(&c[d.x / NPB], 1); atomicAdd(&c[d.y / NPB], 1);
      atomicAdd(&c[d.z / NPB], 1); atomicAdd(&c[d.w / NPB], 1);
    } else {
      for (int e = i; e < E; ++e) atomicAdd(&c[dst[e] / NPB], 1);
    }
  }
  __syncthreads();
  for (int t = tid; t < NBUCK; t += 256)
    if (c[t]) atomicAdd(&gcnt[t], c[t]);
}

// ---------------- bucket scan (1 block) ----------------
__global__ __launch_bounds__(512) void bscan_k(const int* __restrict__ gcnt,
                                               int* __restrict__ goff,
                                               int* __restrict__ gcur) {
  __shared__ int s[512];
  int t = threadIdx.x;
  int v = (t < NBUCK) ? gcnt[t] : 0;
  s[t] = v;
  __syncthreads();
  for (int d = 1; d < 512; d <<= 1) {
    int add = (t >= d) ? s[t - d] : 0;
    __syncthreads();
    s[t] += add;
    __syncthreads();
  }
  if (t < NBUCK) {
    int o = s[t] - v;          // exclusive
    goff[t] = o;
    gcur[t] = o;
    if (t == NBUCK - 1) goff[NBUCK] = s[t];
  }
}

// ---------------- bucketed scatter: edges -> bucket-grouped int2 pairs ----
__global__ __launch_bounds__(512) void bscatter_k(const int* __restrict__ src,
                                                  const int* __restrict__ dst,
                                                  int* __restrict__ gcur,
                                                  int2* __restrict__ pairs, int E) {
  __shared__ int lcnt[NBUCK];
  __shared__ int loff[NBUCK];
  __shared__ int lcur[NBUCK];
  __shared__ int lbase[NBUCK];
  __shared__ int s[512];
  __shared__ int s_src[TILE];
  __shared__ int s_dst[TILE];
  __shared__ int s_tgt[TILE];

  int tid = threadIdx.x;
  int tileStart = blockIdx.x * TILE;
  int tileCnt = E - tileStart; if (tileCnt > TILE) tileCnt = TILE;

  for (int t = tid; t < NBUCK; t += 512) lcnt[t] = 0;
  __syncthreads();

  int es[8], ed[8], eb[8];
  int base = tileStart + tid * 8;
  int ne = 0;
  if (base + 7 < E) {
    int4 a0 = *(const int4*)(src + base);
    int4 a1 = *(const int4*)(src + base + 4);
    int4 b0 = *(const int4*)(dst + base);
    int4 b1 = *(const int4*)(dst + base + 4);
    es[0]=a0.x; es[1]=a0.y; es[2]=a0.z; es[3]=a0.w;
    es[4]=a1.x; es[5]=a1.y; es[6]=a1.z; es[7]=a1.w;
    ed[0]=b0.x; ed[1]=b0.y; ed[2]=b0.z; ed[3]=b0.w;
    ed[4]=b1.x; ed[5]=b1.y; ed[6]=b1.z; ed[7]=b1.w;
    ne = 8;
  } else {
    for (int j = 0; j < 8 && base + j < E; ++j) {
      es[j] = src[base + j]; ed[j] = dst[base + j]; ++ne;
    }
  }
  for (int j = 0; j < ne; ++j) {
    eb[j] = ed[j] / NPB;
    atomicAdd(&lcnt[eb[j]], 1);
  }
  __syncthreads();

  int v = (tid < NBUCK) ? lcnt[tid] : 0;
  s[tid] = v;
  __syncthreads();
  for (int d = 1; d < 512; d <<= 1) {
    int add = (tid >= d) ? s[tid - d] : 0;
    __syncthreads();
    s[tid] += add;
    __syncthreads();
  }
  if (tid < NBUCK) {
    int o = s[tid] - v;
    loff[tid] = o;
    lcur[tid] = o;
    if (v) lbase[tid] = atomicAdd(&gcur[tid], v);
  }
  __syncthreads();

  for (int j = 0; j < ne; ++j) {
    int b = eb[j];
    int slot = atomicAdd(&lcur[b], 1);
    s_src[slot] = es[j];
    s_dst[slot] = ed[j];
    s_tgt[slot] = lbase[b] + (slot - loff[b]);
  }
  __syncthreads();

  for (int k = tid; k < tileCnt; k += 512) {
    pairs[s_tgt[k]] = make_int2(s_src[k], s_dst[k]);
  }
}

// ---------------- regroup: bucket-grouped pairs -> node-sorted CSR ----------
__global__ __launch_bounds__(256) void regroup_k(const int* __restrict__ goff,
                                                 const int2* __restrict__ pairs,
                                                 int* __restrict__ csr,
                                                 int* __restrict__ off,
                                                 int* __restrict__ cnt,
                                                 float* __restrict__ inv, int n) {
  __shared__ int lcnt[NPB];
  __shared__ int lofs[NPB];
  __shared__ int lcur[NPB];
  __shared__ int s[256];
  __shared__ int stage[CAP];

  int tid = threadIdx.x;
  int b = blockIdx.x;
  int nbase = b * NPB;
  int nn = n - nbase; if (nn > NPB) nn = NPB;
  if (nn <= 0) return;

  int e0 = goff[b], e1 = goff[b + 1];
  int m = e1 - e0;

  for (int t = tid; t < NPB; t += 256) lcnt[t] = 0;
  __syncthreads();

  for (int e = e0 + tid; e < e1; e += 256)
    atomicAdd(&lcnt[pairs[e].y - nbase], 1);
  __syncthreads();

  int v = (tid < NPB) ? lcnt[tid] : 0;
  s[tid] = v;
  __syncthreads();
  for (int d = 1; d < 256; d <<= 1) {
    int add = (tid >= d) ? s[tid - d] : 0;
    __syncthreads();
    s[tid] += add;
    __syncthreads();
  }
  if (tid < NPB) { int o = s[tid] - v; lofs[tid] = o; lcur[tid] = o; }
  __syncthreads();

  for (int e = e0 + tid; e < e1; e += 256) {
    int2 p = pairs[e];
    int slot = atomicAdd(&lcur[p.y - nbase], 1);
    if (slot < CAP) stage[slot] = p.x;
    else csr[e0 + slot] = p.x;       // overflow fallback (correct, slow)
  }
  __syncthreads();

  int mm = m < CAP ? m : CAP;
  for (int k = tid; k < mm; k += 256) csr[e0 + k] = stage[k];
  for (int t = tid; t < nn; t += 256) {
    int c = lcnt[t];
    cnt[nbase + t] = c;
    off[nbase + t] = e0 + lofs[t];
    inv[nbase + t] = 1.0f / (float)(c > 1 ? c : 1);
  }
}

// ---------------- MFMA GEMM: Zh = fp16(X@Wl^T), Ph = fp16(X@Wr^T + b) -------
// One wave per 16 node-rows. D = W_tile(16x32) . X_tile^T per mfma:
//   A-operand = W frag:  W[t*16+(lane&15)][kstep*32 + quad*8 + j]
//   B-operand = X frag:  X[row0+(lane&15)][kstep*32 + quad*8 + j]
//   C/D: col=lane&15 -> node, row=quad*4+reg -> feature (verified layouts).
// Lane stores 4 contiguous fp16 features per tile -> 8B stores, no LDS.
__device__ inline h8 cvt8(const float* p) {
  float4 lo = *(const float4*)p;
  float4 hi = *(const float4*)(p + 4);
  h8 f;
  f[0]=(_Float16)lo.x; f[1]=(_Float16)lo.y; f[2]=(_Float16)lo.z; f[3]=(_Float16)lo.w;
  f[4]=(_Float16)hi.x; f[5]=(_Float16)hi.y; f[6]=(_Float16)hi.z; f[7]=(_Float16)hi.w;
  return f;
}

__global__ __launch_bounds__(256) void gemm_k(const float* __restrict__ X,
                                              const float* __restrict__ Wl,
                                              const float* __restrict__ Wr,
                                              const float* __restrict__ bias,
                                              __half* __restrict__ Zh,
                                              __half* __restrict__ Ph, int n) {
  int tid = threadIdx.x;
  int wave = tid >> 6, lane = tid & 63;
  int m = lane & 15, quad = lane >> 4;
  int row0 = (blockIdx.x * 4 + wave) * 16;
  if (row0 >= n) return;

  // W fragments (A-operand), both matrices, all 4 n-tiles, both k-steps
  h8 wf[2][4][2];
#pragma unroll
  for (int mat = 0; mat < 2; ++mat) {
    const float* W = mat ? Wr : Wl;
#pragma unroll
    for (int t = 0; t < 4; ++t)
#pragma unroll
      for (int s = 0; s < 2; ++s)
        wf[mat][t][s] = cvt8(W + (t * 16 + m) * 64 + s * 32 + quad * 8);
  }

  // X fragments (B-operand)
  int rowm = row0 + m; if (rowm > n - 1) rowm = n - 1;   // clamp (unused lanes)
  const float* xp = X + (size_t)rowm * 64 + quad * 8;
  h8 af0 = cvt8(xp);
  h8 af1 = cvt8(xp + 32);

  f4 accz[4], accp[4];
#pragma unroll
  for (int t = 0; t < 4; ++t) {
    f4 z; z[0]=0.f; z[1]=0.f; z[2]=0.f; z[3]=0.f;
    float4 bl = *(const float4*)(bias + t * 16 + quad * 4);
    f4 p; p[0]=bl.x; p[1]=bl.y; p[2]=bl.z; p[3]=bl.w;
    z = __builtin_amdgcn_mfma_f32_16x16x32_f16(wf[0][t][0], af0, z, 0, 0, 0);
    z = __builtin_amdgcn_mfma_f32_16x16x32_f16(wf[0][t][1], af1, z, 0, 0, 0);
    p = __builtin_amdgcn_mfma_f32_16x16x32_f16(wf[1][t][0], af0, p, 0, 0, 0);
    p = __builtin_amdgcn_mfma_f32_16x16x32_f16(wf[1][t][1], af1, p, 0, 0, 0);
    accz[t] = z;
    accp[t] = p;
  }

  if (row0 + m < n) {
    size_t base = (size_t)(row0 + m) * NFEAT + quad * 4;
#pragma unroll
    for (int t = 0; t < 4; ++t) {
      h4 zv, pv;
#pragma unroll
      for (int r = 0; r < 4; ++r) {
        zv[r] = (_Float16)accz[t][r];
        pv[r] = (_Float16)accp[t][r];
      }
      *(h4*)(Zh + base + t * 16) = zv;
      *(h4*)(Ph + base + t * 16) = pv;
    }
  }
}

// ---------------- CSR gather-mean + epilogue (team-per-node) ----------------
__device__ inline float2 h2f(unsigned u) {
  __half2 h = *reinterpret_cast<__half2*>(&u);
  return __half22float2(h);
}

__global__ __launch_bounds__(256) void agg_k(const int* __restrict__ off,
                                             const int* __restrict__ cnt,
                                             const float* __restrict__ inv,
                                             const int* __restrict__ csr,
                                             const __half* __restrict__ Z,
                                             const __half* __restrict__ Pin,
                                             float* __restrict__ out, int n) {
  int t = blockIdx.x * 256 + threadIdx.x;
  int node = t >> 3;
  if (node >= n) return;
  int q = t & 7;            // feature octet owned by this lane

  int start = off[node];
  int deg = cnt[node];

  float a0=0.f,a1=0.f,a2=0.f,a3=0.f,a4=0.f,a5=0.f,a6=0.f,a7=0.f;
  for (int j = 0; j < deg; ++j) {
    int nb = csr[start + j];                       // team-uniform load
    uint4 raw = *(const uint4*)(Z + (size_t)nb * NFEAT + q * 8);
    float2 f0 = h2f(raw.x), f1 = h2f(raw.y), f2 = h2f(raw.z), f3 = h2f(raw.w);
    a0 += f0.x; a1 += f0.y; a2 += f1.x; a3 += f1.y;
    a4 += f2.x; a5 += f2.y; a6 += f3.x; a7 += f3.y;
  }

  float iv = inv[node];
  uint4 praw = *(const uint4*)(Pin + (size_t)node * NFEAT + q * 8);
  float2 p0 = h2f(praw.x), p1 = h2f(praw.y), p2 = h2f(praw.z), p3 = h2f(praw.w);
  float4 r0, r1;
  r0.x = fmaxf(a0 * iv + p0.x, 0.f);
  r0.y = fmaxf(a1 * iv + p0.y, 0.f);
  r0.z = fmaxf(a2 * iv + p1.x, 0.f);
  r0.w = fmaxf(a3 * iv + p1.y, 0.f);
  r1.x = fmaxf(a4 * iv + p2.x, 0.f);
  r1.y = fmaxf(a5 * iv + p2.y, 0.f);
  r1.z = fmaxf(a6 * iv + p3.x, 0.f);
  r1.w = fmaxf(a7 * iv + p3.y, 0.f);
  float* op = &out[(size_t)node * NFEAT + q * 8];
  *(float4*)(op) = r0;
  *(float4*)(op + 4) = r1;
}

// ---------------- launcher ----------------
extern "C" void kernel_launch(void* const* d_in, const int* in_sizes, int n_in,
                              void* d_out, int out_size, void* d_ws, size_t ws_size,
                              hipStream_t stream) {
  const float* x   = (const float*)d_in[0];
  const int*   ei  = (const int*)d_in[1];
  const float* W1l = (const float*)d_in[2];
  const float* b1  = (const float*)d_in[3];
  const float* W1r = (const float*)d_in[4];
  const float* W2l = (const float*)d_in[5];
  const float* b2  = (const float*)d_in[6];
  const float* W2r = (const float*)d_in[7];
  float* out = (float*)d_out;

  int N = in_sizes[0] / NFEAT;     // 100000
  int E = in_sizes[1] / 2;         // 1600000
  const int* srcp = ei;
  const int* dstp = ei + E;

  char* w = (char*)d_ws;
  int2*   pairs = (int2*)w;   w += (size_t)E * 8;
  int*    csr   = (int*)w;    w += (size_t)E * 4;
  __half* Zh    = (__half*)w; w += (size_t)N * NFEAT * 2;
  __half* Ph    = (__half*)w; w += (size_t)N * NFEAT * 2;
  float*  H     = (float*)w;  w += (size_t)N * NFEAT * 4;
  int*    off   = (int*)w;    w += (size_t)N * 4;
  int*    cnt   = (int*)w;    w += (size_t)N * 4;
  float*  inv   = (float*)w;  w += (size_t)N * 4;
  int*    gcnt  = (int*)w;    w += NBUCK * 4;
  int*    goff  = (int*)w;    w += (NBUCK + 1) * 4;
  int*    gcur  = (int*)w;    w += NBUCK * 4;
  if ((size_t)(w - (char*)d_ws) > ws_size) return;

  hipMemsetAsync(gcnt, 0, NBUCK * 4, stream);

  bcount_k<<<256, 256, 0, stream>>>(dstp, gcnt, E);
  bscan_k<<<1, 512, 0, stream>>>(gcnt, goff, gcur);
  int sb = (E + TILE - 1) / TILE;
  bscatter_k<<<sb, 512, 0, stream>>>(srcp, dstp, gcur, pairs, E);
  regroup_k<<<NBUCK, 256, 0, stream>>>(goff, pairs, csr, off, cnt, inv, N);

  int gb = (N + 63) / 64;          // 4 waves/block x 16 rows/wave
  int ab = (N * 8 + 255) / 256;    // 8 lanes per node

  // layer 1: Zh = fp16(x@W1l^T) ; Ph = fp16(x@W1r^T + b1) ; H = relu(agg + P)
  gemm_k<<<gb, 256, 0, stream>>>(x, W1l, W1r, b1, Zh, Ph, N);
  agg_k<<<ab, 256, 0, stream>>>(off, cnt, inv, csr, Zh, Ph, H, N);
  // layer 2 -> d_out
  gemm_k<<<gb, 256, 0, stream>>>(H, W2l, W2r, b2, Zh, Ph, N);
  agg_k<<<ab, 256, 0, stream>>>(off, cnt, inv, csr, Zh, Ph, out, N);
}